// Round 1
// 347.250 us; speedup vs baseline: 1.0356x; 1.0356x over previous
//
#include <hip/hip_runtime.h>

typedef _Float16 half8 __attribute__((ext_vector_type(8)));
typedef _Float16 half4 __attribute__((ext_vector_type(4)));
typedef _Float16 half2v __attribute__((ext_vector_type(2)));
typedef float floatx4 __attribute__((ext_vector_type(4)));

// Problem constants (fixed by reference)
constexpr int NN = 100000;   // nodes
constexpr int EE = 1600000;  // edges
constexpr int NBK = 196;     // partition buckets: ceil(100000/512)
constexpr int CHUNK = 3125;  // edges per k_part block (EE/512)
constexpr int CAPB = 12288;  // per-bucket slab capacity (mean 8192, sigma~90)
constexpr int NDCAP = 48;    // per-node LDS edge cap (mean deg 16; mult of 16)

// ---- pass A: block-local counting sort into coarse buckets (dst>>9) ----
// Buckets self-allocate into fixed slabs part[bk*CAPB ...]; gcur[bk] counts.
// record: x = (dst<<15) | (src>>2); y = (src&3) | (et<<2) | (norm_fp16<<5)
__global__ __launch_bounds__(256) void k_part(const int* __restrict__ dst,
                                              const int* __restrict__ src,
                                              const int* __restrict__ etype,
                                              const float* __restrict__ norm,
                                              int* __restrict__ gcur,
                                              int2* __restrict__ part) {
  __shared__ int2 ldata[CHUNK];             // 25000 B
  __shared__ unsigned char lbkt[CHUNK];     // 3125 B
  __shared__ int lhist[NBK], lbase[NBK + 1], lcur[NBK], gbase[NBK];
  __shared__ int sh[256];
  const int tid = threadIdx.x;
  const int e0 = blockIdx.x * CHUNK;

  for (int b = tid; b < NBK; b += 256) lhist[b] = 0;
  __syncthreads();
  for (int i = tid; i < CHUNK; i += 256)
    atomicAdd(&lhist[dst[e0 + i] >> 9], 1);
  __syncthreads();
  {
    const int v = (tid < NBK) ? lhist[tid] : 0;
    sh[tid] = v;
    __syncthreads();
    int run = v;
    for (int d = 1; d < 256; d <<= 1) {
      int t = (tid >= d) ? sh[tid - d] : 0;
      __syncthreads();
      run += t;
      sh[tid] = run;
      __syncthreads();
    }
    if (tid < NBK) {
      lbase[tid] = run - v;
      lcur[tid] = 0;
      gbase[tid] = tid * CAPB + atomicAdd(&gcur[tid], v);
    }
    if (tid == 0) lbase[NBK] = CHUNK;
  }
  __syncthreads();
  for (int i = tid; i < CHUNK; i += 256) {
    const int e = e0 + i;
    const int d = dst[e], s = src[e], et = etype[e];
    const _Float16 nh = (_Float16)norm[e];
    const unsigned short n16 = __builtin_bit_cast(unsigned short, nh);
    const int bk = d >> 9;
    const int pos = lbase[bk] + atomicAdd(&lcur[bk], 1);
    ldata[pos] = make_int2((d << 15) | (s >> 2), (s & 3) | (et << 2) | ((int)n16 << 5));
    lbkt[pos] = (unsigned char)bk;
  }
  __syncthreads();
  for (int i = tid; i < CHUNK; i += 256) {
    const int bk = (int)lbkt[i];
    part[gbase[bk] + (i - lbase[bk])] = ldata[i];
  }
}

// ---- pass B: per-bucket node histogram + scan -> off[]; exact placement ----
// 512 threads; bucket's global edge base computed in-block (sum of gcur[<bk]).
__global__ __launch_bounds__(512) void k_part2(const int* __restrict__ gcur,
                                               const int2* __restrict__ part,
                                               int* __restrict__ off,
                                               int2* __restrict__ em) {
  __shared__ int hcnt[512];
  __shared__ int wred[8];
  __shared__ int swsum[8];
  const int tid = threadIdx.x;
  const int bk = blockIdx.x;
  const int nb0 = bk << 9;
  const int2* __restrict__ pp = part + (size_t)bk * CAPB;

  // base = sum_{j<bk} gcur[j]  (block-wide reduction)
  {
    int pv = (tid < bk) ? gcur[tid] : 0;
    for (int d = 32; d > 0; d >>= 1) pv += __shfl_down(pv, d);
    if ((tid & 63) == 0) wred[tid >> 6] = pv;
  }
  hcnt[tid] = 0;
  __syncthreads();
  int base = 0;
#pragma unroll
  for (int w = 0; w < 8; ++w) base += wred[w];
  const int cntb = gcur[bk];

  for (int i = tid; i < cntb; i += 512)
    atomicAdd(&hcnt[(((unsigned)pp[i].x) >> 15) & 511], 1);
  __syncthreads();
  // exclusive scan of 512 counts (wave scans + wave-sum prefix)
  const int v = hcnt[tid];
  int incl = v;
  for (int d = 1; d < 64; d <<= 1) {
    const int t = __shfl_up(incl, d);
    if ((tid & 63) >= d) incl += t;
  }
  if ((tid & 63) == 63) swsum[tid >> 6] = incl;
  __syncthreads();
  int pre = 0;
  for (int w = 0; w < (tid >> 6); ++w) pre += swsum[w];
  const int excl = pre + incl - v;  // bucket-local exclusive offset
  {
    const int n = nb0 + tid;
    if (n < NN) off[n] = base + excl;
  }
  if (bk == NBK - 1 && tid == 0) off[NN] = EE;
  hcnt[tid] = excl;  // cursors (all reads of hcnt done pre-sync)
  __syncthreads();
  for (int i = tid; i < cntb; i += 512) {
    const int2 r = pp[i];
    const int d = ((unsigned)r.x) >> 15;
    const int s = ((r.x & 0x7FFF) << 2) | (r.y & 3);
    const int et = (r.y >> 2) & 7;
    const unsigned short n16 = (unsigned short)((r.y >> 5) & 0xFFFF);
    const float nf = (float)__builtin_bit_cast(_Float16, n16);
    const int pos = atomicAdd(&hcnt[d & 511], 1);
    em[base + pos] = make_int2((et << 20) | s, __float_as_int(nf));
  }
}

// ---------------- prep: fp16 conversions + gcur zeroing ----------------

__global__ __launch_bounds__(256) void k_prep(const float* __restrict__ h,
                                              _Float16* __restrict__ hh,
                                              const float* __restrict__ b0,
                                              const float* __restrict__ b1,
                                              const float* __restrict__ b2,
                                              _Float16* __restrict__ bbt,
                                              int* __restrict__ gcur) {
  const int bx = blockIdx.x;
  if (bx == 0 && threadIdx.x < NBK) gcur[threadIdx.x] = 0;
  if (bx < 6250) {
    const int i = bx * 256 + threadIdx.x;
    const float4 v = *(const float4*)&h[(size_t)i * 4];
    half4 o = {(_Float16)v.x, (_Float16)v.y, (_Float16)v.z, (_Float16)v.w};
    *(half4*)&hh[(size_t)i * 4] = o;
  } else {
    const int g = (bx - 6250) >> 6;
    const int idx = ((bx - 6250) & 63) * 256 + threadIdx.x;
    const float* bases = (g == 0) ? b0 : (g == 1) ? b1 : b2;
    const int o = idx >> 8, k = idx & 255;
    const int b = k >> 6, i = k & 63;
    bbt[g * 16384 + idx] = (_Float16)bases[b * 4096 + i * 64 + o];
  }
}

// ---------------- fused layer: gather + basis-GEMM (MFMA) ----------------
// Block = 16 dst nodes. Staging precomputes per-edge coefficient pairs
// {c0,c1},{c2,c3} (fp16, 8B/slot; splat to {ci,ci} in-register via
// shufflevector -> VOP3P op_sel, zero extra instrs) + src, zero-padded per
// node. Main loop: 2 edges per wave (32-lane groups), 16-slot batches
// (8 gathers in flight), 4 v_pk_fma_f16 per edge, no cvt. Cross-group
// combine via shfl_xor(32). Then 16x16 MFMA chain (K=256) per wave.
// LDS ~17.9KB -> 8 blocks/CU (32 waves, occupancy cap) vs 24KB/6 before.
__global__ __launch_bounds__(256, 8) void k_layer(const _Float16* __restrict__ hh,
                                                  const int* __restrict__ off,
                                                  const int2* __restrict__ em,
                                                  const float* __restrict__ wcomp,
                                                  const _Float16* __restrict__ bbt,
                                                  _Float16* __restrict__ out16,
                                                  float* __restrict__ out32) {
  __shared__ _Float16 Ash[16 * 264];   // 8448 B
  __shared__ int  ems_s[16 * NDCAP];   // 3072 B: src per slot
  __shared__ int2 ems_c[16 * NDCAP];   // 6144 B: coeff pairs {c0,c1},{c2,c3}
  __shared__ float4 wcs[8];
  __shared__ int offs[17];
  __shared__ int ovf;
  const int tid = threadIdx.x;
  const int lane = tid & 63;
  const int wv = tid >> 6;
  const int n0 = blockIdx.x * 16;

  if (tid < 17) offs[tid] = off[n0 + tid];
  if (tid == 0) ovf = 0;
  if (tid < 8) wcs[tid] = ((const float4*)wcomp)[tid];
  for (int i = tid; i < 16 * NDCAP; i += 256) {
    ems_s[i] = 0;
    ems_c[i] = make_int2(0, 0);
  }
  __syncthreads();

  const int e0 = offs[0];
  const int len = offs[16] - e0;
  for (int i = tid; i < len; i += 256) {
    const int g = e0 + i;
    const int2 r = em[g];
    int lo = 0, hi = 15;
    while (lo < hi) { const int mid = (lo + hi + 1) >> 1; if (offs[mid] <= g) lo = mid; else hi = mid - 1; }
    const int rank = g - offs[lo];
    const int et = r.x >> 20;
    const int s = r.x & 0xFFFFF;
    const float nf = __int_as_float(r.y);
    const float4 w = wcs[et];
    const _Float16 c0 = (_Float16)(nf * w.x), c1 = (_Float16)(nf * w.y);
    const _Float16 c2 = (_Float16)(nf * w.z), c3 = (_Float16)(nf * w.w);
    const half2v p01 = {c0, c1}, p23 = {c2, c3};
    if (rank < NDCAP) {
      ems_s[lo * NDCAP + rank] = s;
      ems_c[lo * NDCAP + rank] = make_int2(
          __builtin_bit_cast(int, p01), __builtin_bit_cast(int, p23));
    } else ovf = 1;
  }
  __syncthreads();

  if (!ovf) {
    // fast path: fp16 packed accumulation, zero-padded 16-slot batches
    const int fl = lane & 31;   // feature pair index (feats 2fl, 2fl+1)
    const int eg = lane >> 5;   // edge group 0/1
    const half2v* __restrict__ hp = (const half2v*)hh;
    for (int q = 0; q < 4; ++q) {
      const int m = wv * 4 + q;
      const int cnt = offs[m + 1] - offs[m];
      const int nbat = (cnt + 15) >> 4;
      const int* sp = &ems_s[m * NDCAP + eg * 8];
      const int2* cp = &ems_c[m * NDCAP + eg * 8];
      half2v a0 = {0, 0}, a1 = {0, 0}, a2 = {0, 0}, a3 = {0, 0};
      for (int b = 0; b < nbat; ++b) {
        int s8[8];
#pragma unroll
        for (int j = 0; j < 8; ++j) s8[j] = sp[b * 16 + j];
        half2v hv[8];
#pragma unroll
        for (int j = 0; j < 8; ++j)
          hv[j] = hp[(unsigned)s8[j] * 32u + fl];
#pragma unroll
        for (int j = 0; j < 8; ++j) {
          const int2 cc = cp[b * 16 + j];
          const half2v c01 = __builtin_bit_cast(half2v, cc.x);
          const half2v c23 = __builtin_bit_cast(half2v, cc.y);
          a0 = a0 + hv[j] * __builtin_shufflevector(c01, c01, 0, 0);
          a1 = a1 + hv[j] * __builtin_shufflevector(c01, c01, 1, 1);
          a2 = a2 + hv[j] * __builtin_shufflevector(c23, c23, 0, 0);
          a3 = a3 + hv[j] * __builtin_shufflevector(c23, c23, 1, 1);
        }
      }
      a0 = a0 + __builtin_bit_cast(half2v, __shfl_xor(__builtin_bit_cast(int, a0), 32));
      a1 = a1 + __builtin_bit_cast(half2v, __shfl_xor(__builtin_bit_cast(int, a1), 32));
      a2 = a2 + __builtin_bit_cast(half2v, __shfl_xor(__builtin_bit_cast(int, a2), 32));
      a3 = a3 + __builtin_bit_cast(half2v, __shfl_xor(__builtin_bit_cast(int, a3), 32));
      if (eg == 0) {
        _Float16* ar = &Ash[m * 264];
        *(half2v*)&ar[0 * 64 + 2 * fl] = a0;
        *(half2v*)&ar[1 * 64 + 2 * fl] = a1;
        *(half2v*)&ar[2 * 64 + 2 * fl] = a2;
        *(half2v*)&ar[3 * 64 + 2 * fl] = a3;
      }
    }
  } else {
    // slow path (deg > NDCAP): fp32 clamped batches straight from global em
    const _Float16* hl = hh + lane;
    for (int q = 0; q < 4; ++q) {
      const int m = wv * 4 + q;
      const int p0 = offs[m], p1 = offs[m + 1];
      float a0 = 0.f, a1 = 0.f, a2 = 0.f, a3 = 0.f;
      for (int p = p0; p < p1; p += 8) {
#pragma unroll
        for (int j = 0; j < 8; ++j) {
          const bool live = (p + j < p1);
          const int idx = live ? p + j : p1 - 1;
          const int2 mm = em[idx];
          const float hv = (float)hl[(size_t)(mm.x & 0xFFFFF) << 6];
          const float wn = live ? __int_as_float(mm.y) : 0.f;
          const float4 w = wcs[mm.x >> 20];
          const float t = wn * hv;
          a0 = fmaf(t, w.x, a0); a1 = fmaf(t, w.y, a1);
          a2 = fmaf(t, w.z, a2); a3 = fmaf(t, w.w, a3);
        }
      }
      _Float16* ar = &Ash[m * 264];
      ar[lane]       = (_Float16)a0;
      ar[64 + lane]  = (_Float16)a1;
      ar[128 + lane] = (_Float16)a2;
      ar[192 + lane] = (_Float16)a3;
    }
  }
  __syncthreads();

  // MFMA: C[16 nodes][16 outs] per wave, outs = wv*16..+15, K = 256.
  const int col = lane & 15;
  const int quad = lane >> 4;
  const int obase = wv * 16 + col;
  const _Float16* ap = &Ash[col * 264 + quad * 8];
  const _Float16* bp = &bbt[(size_t)obase * 256 + quad * 8];
  floatx4 acc = {0.f, 0.f, 0.f, 0.f};
#pragma unroll
  for (int s = 0; s < 8; ++s) {
    const half8 af = *(const half8*)(ap + s * 32);
    const half8 bf = *(const half8*)(bp + s * 32);
    acc = __builtin_amdgcn_mfma_f32_16x16x32_f16(af, bf, acc, 0, 0, 0);
  }
  if (out16) {
#pragma unroll
    for (int r = 0; r < 4; ++r) {
      const float c = fmaxf(acc[r], 0.f);
      out16[(size_t)(n0 + quad * 4 + r) * 64 + obase] = (_Float16)c;
    }
  } else {
#pragma unroll
    for (int r = 0; r < 4; ++r) {
      out32[(size_t)(n0 + quad * 4 + r) * 64 + obase] = acc[r];
    }
  }
}

// decoder: rec[n] = b2 + sum_o relu(b1[o] + henc[n,:]@w1[:,o]) * w2[o]
__global__ __launch_bounds__(256) void k_dec(const float* __restrict__ henc,
                                             const float* __restrict__ w1,
                                             const float* __restrict__ b1,
                                             const float* __restrict__ w2,
                                             const float* __restrict__ b2,
                                             float* __restrict__ rec) {
  __shared__ float w1s[64 * 64];
  __shared__ float hs[16 * 68];
  const int tid = threadIdx.x;
  for (int r = tid; r < 1024; r += 256)
    *(float4*)&w1s[r * 4] = *(const float4*)&w1[r * 4];
  const int og = tid & 15;
  const int nl = tid >> 4;
  const float4 wv2 = *(const float4*)&w2[og * 4];
  const float4 bv1 = *(const float4*)&b1[og * 4];
  const float b2v = b2[0];
  for (int t0 = blockIdx.x * 16; t0 < NN; t0 += gridDim.x * 16) {
    __syncthreads();
    {
      const float4 hv = *(const float4*)&henc[(size_t)t0 * 64 + tid * 4];
      *(float4*)&hs[(tid >> 4) * 68 + (tid & 15) * 4] = hv;
    }
    __syncthreads();
    float4 acc = bv1;
    const float* hr = &hs[nl * 68];
#pragma unroll 8
    for (int i = 0; i < 64; ++i) {
      const float hv = hr[i];
      const float4 wv = *(const float4*)&w1s[i * 64 + og * 4];
      acc.x = fmaf(hv, wv.x, acc.x); acc.y = fmaf(hv, wv.y, acc.y);
      acc.z = fmaf(hv, wv.z, acc.z); acc.w = fmaf(hv, wv.w, acc.w);
    }
    acc.x = fmaxf(acc.x, 0.f); acc.y = fmaxf(acc.y, 0.f);
    acc.z = fmaxf(acc.z, 0.f); acc.w = fmaxf(acc.w, 0.f);
    float v = acc.x * wv2.x + acc.y * wv2.y + acc.z * wv2.z + acc.w * wv2.w;
    v += __shfl_xor(v, 1); v += __shfl_xor(v, 2);
    v += __shfl_xor(v, 4); v += __shfl_xor(v, 8);
    if (og == 0) rec[t0 + nl] = v + b2v;
  }
}

// ---------------- launch ----------------

extern "C" void kernel_launch(void* const* d_in, const int* in_sizes, int n_in,
                              void* d_out, int out_size, void* d_ws, size_t ws_size,
                              hipStream_t stream) {
  const float* h     = (const float*)d_in[0];
  const int*   src   = (const int*)d_in[1];
  const int*   dst   = (const int*)d_in[2];
  const int*   etype = (const int*)d_in[3];
  const float* norm  = (const float*)d_in[4];
  const float* bases[3] = {(const float*)d_in[5], (const float*)d_in[7], (const float*)d_in[9]};
  const float* wcomp[3] = {(const float*)d_in[6], (const float*)d_in[8], (const float*)d_in[10]};
  const float* dw1 = (const float*)d_in[11];
  const float* db1 = (const float*)d_in[12];
  const float* dw2 = (const float*)d_in[13];
  const float* db2 = (const float*)d_in[14];

  float* rec  = (float*)d_out;        // [N]
  float* henc = (float*)d_out + NN;   // [N,64] fp32 (layer-3 output)

  // workspace carve-up (16B-aligned)
  char* ws = (char*)d_ws;
  int*      off    = (int*)(ws + 0);              // (N+1) ints
  int*      gcur   = (int*)(ws + 400512);         // NBK bucket counters
  int2*     em     = (int2*)(ws + 402560);        // E records, dst-sorted
  _Float16* hh     = (_Float16*)(ws + 13202560);  // [N][64] fp16
  _Float16* h1f    = (_Float16*)(ws + 26002560);  // [N][64] fp16
  _Float16* h2f    = (_Float16*)(ws + 38802560);  // [N][64] fp16
  _Float16* bbt    = (_Float16*)(ws + 51602560);  // [3][64][256] fp16
  int2*     part   = (int2*)h1f;                  // NBK slabs x CAPB records
                                                  // (19.3 MB; consumed in
                                                  //  k_part2 before h1f/h2f
                                                  //  are written by layers)

  // ---- fp16 prep (h + bases) + gcur zeroing ----
  k_prep<<<6250 + 192, 256, 0, stream>>>(h, hh, bases[0], bases[1], bases[2], bbt, gcur);

  // ---- build dst-sorted CSR (self-allocating two-phase partition) ----
  k_part<<<512, 256, 0, stream>>>(dst, src, etype, norm, gcur, part);
  k_part2<<<NBK, 512, 0, stream>>>(gcur, part, off, em);

  // ---- fused layers ----
  k_layer<<<NN / 16, 256, 0, stream>>>(hh,  off, em, wcomp[0], bbt,         h1f, nullptr);
  k_layer<<<NN / 16, 256, 0, stream>>>(h1f, off, em, wcomp[1], bbt + 16384, h2f, nullptr);
  k_layer<<<NN / 16, 256, 0, stream>>>(h2f, off, em, wcomp[2], bbt + 32768, nullptr, henc);

  // ---- decoder ----
  k_dec<<<256, 256, 0, stream>>>(henc, dw1, db1, dw2, db2, rec);
}